// Round 8
// baseline (105.545 us; speedup 1.0000x reference)
//
#include <hip/hip_runtime.h>

typedef unsigned int u32;
typedef unsigned short u16;

#define B_   2
#define CIN  256
#define COUT 256
#define PD   34
#define PLANE (PD*PD)        // 1156
#define P3   (PD*PD*PD)      // 39304
#define SPAT 32768           // 32*32*32

// xt2: [b][kg(32)][p(P3)][8]  (granule = 8 cin = 16B)
#define XT_BYTES ((size_t)B_ * 32 * P3 * 8 * 2)
#define WB_OFF_BYTES XT_BYTES

typedef __attribute__((ext_vector_type(8)))  short bf16x8;
typedef __attribute__((ext_vector_type(8)))  u16   u16x8;
typedef __attribute__((ext_vector_type(16))) float f32x16;

__device__ __forceinline__ u16 f2bf(float f) {
  union { float f; u32 u; } v; v.f = f;
  u32 r = v.u + 0x7FFFu + ((v.u >> 16) & 1u);   // RNE
  return (u16)(r >> 16);
}

__device__ __forceinline__ void gload_lds16(const void* g, void* l) {
  __builtin_amdgcn_global_load_lds(
      (const __attribute__((address_space(1))) u32*)g,
      (__attribute__((address_space(3))) u32*)l,
      16, 0, 0);
}

__device__ __forceinline__ int tapOff(u32 d) {
  return (d == 1) ? -PLANE : (d == 2) ? PLANE
       : (d == 3) ? -PD    : (d == 4) ? PD
       : (d == 5) ? -1     : (d == 6) ? 1 : 0;
}

// ---------------- zero only the pad border of xt2 ---------------------------
__global__ void zero_border(u16* __restrict__ xt) {
  u32 idx = blockIdx.x * 256u + threadIdx.x;   // 64 * P3 granules
  if (idx >= 64u * (u32)P3) return;
  u32 bk = idx & 63u;                          // b*32 + kg
  u32 p  = idx >> 6;
  u32 t = p / PLANE, rem = p - t * PLANE, r = rem / PD, c = rem - r * PD;
  if (!((t == 0) | (t == 33) | (r == 0) | (r == 33) | (c == 0) | (c == 33)))
    return;
  *(u16x8*)(xt + ((size_t)bk * P3 + p) * 8) = (u16x8)0;
}

// ---------------- W fp32 -> bf16, wb2[d][kg][o][8] ---------------------------
__global__ void convert_w(const float* __restrict__ W, u16* __restrict__ wb) {
  u32 idx = blockIdx.x * 256u + threadIdx.x;   // 7*32*256 = 57344
  u32 o = idx & 255u, kgd = idx >> 8;          // kgd = d*32 + kg
  u32 kg = kgd & 31u, d = kgd >> 5;
  const float* src = W + (size_t)(d * 256u + o) * CIN + kg * 8u;
  float4 f0 = ((const float4*)src)[0];
  float4 f1 = ((const float4*)src)[1];
  u16x8 v;
  v[0] = f2bf(f0.x); v[1] = f2bf(f0.y); v[2] = f2bf(f0.z); v[3] = f2bf(f0.w);
  v[4] = f2bf(f1.x); v[5] = f2bf(f1.y); v[6] = f2bf(f1.z); v[7] = f2bf(f1.w);
  *(u16x8*)(wb + (size_t)idx * 8) = v;
}

// ------- x (b,i,t,r,c) fp32 -> xt2[b][kg][p][8] bf16 ------------------------
__global__ void transpose_pad(const float* __restrict__ x, u16* __restrict__ xt) {
  __shared__ __align__(16) u16 tile[32][256];
  u32 wg = blockIdx.x;                       // 2048 = B*32*32
  u32 b = wg >> 10, t = (wg >> 5) & 31, r = wg & 31;
  u32 i = threadIdx.x;
  const float* src = x + ((size_t)(b * CIN + i) * SPAT + t * 1024u + r * 32u);
#pragma unroll
  for (int q = 0; q < 8; ++q) {
    float4 f = ((const float4*)src)[q];
    tile[q * 4 + 0][i] = f2bf(f.x);
    tile[q * 4 + 1][i] = f2bf(f.y);
    tile[q * 4 + 2][i] = f2bf(f.z);
    tile[q * 4 + 3][i] = f2bf(f.w);
  }
  __syncthreads();
  u32 c = threadIdx.x >> 3, chunk = threadIdx.x & 7;   // chunk -> kg 4*chunk..+3
  u32 p = ((t + 1) * PD + (r + 1)) * PD + 1 + c;
  const uint4* s = (const uint4*)&tile[c][chunk * 32u];
#pragma unroll
  for (int j = 0; j < 4; ++j) {
    u32 kg = chunk * 4u + (u32)j;
    *(uint4*)(xt + ((size_t)(b * 32u + kg) * P3 + p) * 8) = s[j];
  }
}

// ---------------- main: 4-wave 128x256 tile, BK=32, 2 blocks/CU -------------
// grid 512 (2 blocks/CU): block = 128 cout (ch half) x 256 spatial. 56 K-tiles
// of BK=32. Per tile: STAGE(T+1) issue-first (6 gload_lds/wave), 12
// ds_read_b128/wave, 16 MFMA 32x32x16/wave, ONE __syncthreads (its vmcnt(0)
// drain overlaps the co-resident block's compute - the m114 TLP mechanism).
__global__ __launch_bounds__(256, 2)
void conv_main(const u16* __restrict__ xt, const u16* __restrict__ wb,
               float* __restrict__ out) {
  __shared__ __align__(16) u16 ldsA[2][4][128][8];   // 16 KiB
  __shared__ __align__(16) u16 ldsB[2][4][256][8];   // 32 KiB

  u32 bid = blockIdx.x;
  u32 id2 = (bid & 7) * 64u + (bid >> 3);    // XCD swizzle (512 % 8 == 0)
  u32 ch = id2 & 1u;                          // cout half (pairs co-XCD)
  u32 sp = id2 >> 1;                          // 0..255 spatial tile
  u32 b  = sp >> 7;
  u32 t  = (sp >> 2) & 31;
  u32 r0 = (sp & 3) * 8u;

  u32 tid = threadIdx.x;
  u32 lane = tid & 63, wave = tid >> 6;       // 4 waves
  u32 wm = wave >> 1, wn = wave & 1;          // 2(m) x 2(n) wave grid
  u32 l31 = lane & 31u, lq2 = lane >> 5;

  const u16* xb = xt + (size_t)b * 32u * P3 * 8u;
  u32 pBase = ((t + 1) * PD + (r0 + 1)) * PD + 1;

  // wave stages kb = wave. A: rows rc*64+lane (rc 0,1); B: rows sc*64+lane.
#define STAGE(KT) do {                                                        \
    u32 kt_ = (u32)(KT), buf_ = kt_ & 1u;                                     \
    u32 d_ = kt_ >> 3, kg_ = (kt_ & 7u) * 4u + wave;                          \
    const u16* gA_ = wb + ((size_t)(d_ * 32u + kg_) * 256u                    \
                           + ch * 128u + lane) * 8u;                          \
    gload_lds16(gA_,            &ldsA[buf_][wave][0][0]);                     \
    gload_lds16(gA_ + 64u * 8u, &ldsA[buf_][wave][64][0]);                    \
    u32 pT_ = (u32)((int)pBase + tapOff(d_));                                 \
    const u16* gB_ = xb + ((size_t)kg_ * P3 + pT_                             \
                           + (lane >> 5) * (u32)PD + (lane & 31u)) * 8u;      \
    gload_lds16(gB_,                       &ldsB[buf_][wave][0][0]);          \
    gload_lds16(gB_ + 2u * (u32)PD * 8u,   &ldsB[buf_][wave][64][0]);         \
    gload_lds16(gB_ + 4u * (u32)PD * 8u,   &ldsB[buf_][wave][128][0]);        \
    gload_lds16(gB_ + 6u * (u32)PD * 8u,   &ldsB[buf_][wave][192][0]);        \
  } while (0)

  f32x16 acc[2][4];
#pragma unroll
  for (int i = 0; i < 2; ++i)
#pragma unroll
    for (int j = 0; j < 4; ++j) acc[i][j] = (f32x16)0.0f;

#define MF(A, Bv, C) __builtin_amdgcn_mfma_f32_32x32x16_bf16(A, Bv, C, 0, 0, 0)

  // frag(ks,mt/nt): kb = ks*2 + lq2; A row = wm*64+mt*32+l31 ; B row =
  // wn*128+nt*32+l31. acc[mt][nt].
#define COMPUTE(BUF) do {                                                     \
    bf16x8 a[2][2], bv[2][4];                                                 \
    _Pragma("unroll")                                                         \
    for (int ks = 0; ks < 2; ++ks) {                                          \
      _Pragma("unroll")                                                       \
      for (int mt = 0; mt < 2; ++mt)                                          \
        a[ks][mt] = *(const bf16x8*)&ldsA[BUF][ks * 2 + lq2]                  \
            [wm * 64 + mt * 32 + l31][0];                                     \
      _Pragma("unroll")                                                       \
      for (int nt = 0; nt < 4; ++nt)                                          \
        bv[ks][nt] = *(const bf16x8*)&ldsB[BUF][ks * 2 + lq2]                 \
            [wn * 128 + nt * 32 + l31][0];                                    \
    }                                                                         \
    __builtin_amdgcn_s_setprio(1);                                            \
    _Pragma("unroll")                                                         \
    for (int ks = 0; ks < 2; ++ks)                                            \
      _Pragma("unroll")                                                       \
      for (int mt = 0; mt < 2; ++mt)                                          \
        _Pragma("unroll")                                                     \
        for (int nt = 0; nt < 4; ++nt)                                        \
          acc[mt][nt] = MF(a[ks][mt], bv[ks][nt], acc[mt][nt]);               \
    __builtin_amdgcn_s_setprio(0);                                            \
  } while (0)

  STAGE(0);
  __syncthreads();

#pragma unroll 1
  for (int T = 0; T < 56; ++T) {
    if (T + 1 < 56) STAGE(T + 1);     // issue-first, into buf^1
    COMPUTE((u32)T & 1u);
    __syncthreads();                  // drains vmcnt(0): buf^1 ready, buf free
  }

#undef COMPUTE
#undef MF
#undef STAGE

  // epilogue: 32x32 C/D: col = lane&31 (spatial), row = (reg&3)+8*(reg>>2)
  //           +4*(lane>>5) (cout)
  u32 rbase = lq2 * 4u;
  float* ob = out + (size_t)(b * COUT + ch * 128u + wm * 64u) * SPAT
                  + t * 1024u + r0 * 32u + wn * 128u + l31;
#pragma unroll
  for (int mt = 0; mt < 2; ++mt)
#pragma unroll
    for (int nt = 0; nt < 4; ++nt) {
      f32x16 v = acc[mt][nt];
#pragma unroll
      for (int reg = 0; reg < 16; ++reg) {
        u32 row = (u32)(reg & 3) + 8u * (u32)(reg >> 2) + rbase;
        ob[(size_t)(mt * 32u + row) * SPAT + nt * 32u] = v[reg];
      }
    }
}

extern "C" void kernel_launch(void* const* d_in, const int* in_sizes, int n_in,
                              void* d_out, int out_size, void* d_ws, size_t ws_size,
                              hipStream_t stream) {
  const float* x = (const float*)d_in[0];
  const float* W = (const float*)d_in[1];
  float* out = (float*)d_out;
  u16* xt  = (u16*)d_ws;
  u16* wbf = (u16*)((char*)d_ws + WB_OFF_BYTES);

  u32 zThreads = 64u * (u32)P3;
  hipLaunchKernelGGL(zero_border,   dim3((zThreads + 255) / 256), dim3(256), 0, stream, xt);
  hipLaunchKernelGGL(convert_w,     dim3(224),  dim3(256), 0, stream, W, wbf);
  hipLaunchKernelGGL(transpose_pad, dim3(2048), dim3(256), 0, stream, x, xt);
  hipLaunchKernelGGL(conv_main,     dim3(512),  dim3(256), 0, stream, xt, wbf, out);
}

// Round 9
// 96.586 us; speedup vs baseline: 1.0928x; 1.0928x over previous
//
#include <hip/hip_runtime.h>

typedef unsigned int u32;
typedef unsigned short u16;

#define B_   2
#define CIN  256
#define COUT 256
#define PD   34
#define PLANE (PD*PD)        // 1156
#define P3   (PD*PD*PD)      // 39304
#define SPAT 32768           // 32*32*32

// xt2: [b][kg(32)][p(P3)][8]  (granule = 8 cin = 16B)
#define XT_BYTES ((size_t)B_ * 32 * P3 * 8 * 2)
#define WB_OFF_BYTES XT_BYTES

typedef __attribute__((ext_vector_type(8)))  short bf16x8;
typedef __attribute__((ext_vector_type(8)))  u16   u16x8;
typedef __attribute__((ext_vector_type(16))) float f32x16;

__device__ __forceinline__ u16 f2bf(float f) {
  union { float f; u32 u; } v; v.f = f;
  u32 r = v.u + 0x7FFFu + ((v.u >> 16) & 1u);   // RNE
  return (u16)(r >> 16);
}

__device__ __forceinline__ void gload_lds16(const void* g, void* l) {
  __builtin_amdgcn_global_load_lds(
      (const __attribute__((address_space(1))) u32*)g,
      (__attribute__((address_space(3))) u32*)l,
      16, 0, 0);
}

__device__ __forceinline__ int tapOff(u32 d) {
  return (d == 1) ? -PLANE : (d == 2) ? PLANE
       : (d == 3) ? -PD    : (d == 4) ? PD
       : (d == 5) ? -1     : (d == 6) ? 1 : 0;
}

// ---------------- zero only the pad border of xt2 ---------------------------
__global__ void zero_border(u16* __restrict__ xt) {
  u32 idx = blockIdx.x * 256u + threadIdx.x;   // 64 * P3 granules
  if (idx >= 64u * (u32)P3) return;
  u32 bk = idx & 63u;                          // b*32 + kg
  u32 p  = idx >> 6;
  u32 t = p / PLANE, rem = p - t * PLANE, r = rem / PD, c = rem - r * PD;
  if (!((t == 0) | (t == 33) | (r == 0) | (r == 33) | (c == 0) | (c == 33)))
    return;
  *(u16x8*)(xt + ((size_t)bk * P3 + p) * 8) = (u16x8)0;
}

// ---------------- W fp32 -> bf16, wb2[d][kg][o][8] ---------------------------
__global__ void convert_w(const float* __restrict__ W, u16* __restrict__ wb) {
  u32 idx = blockIdx.x * 256u + threadIdx.x;   // 7*32*256 = 57344
  u32 o = idx & 255u, kgd = idx >> 8;          // kgd = d*32 + kg
  u32 kg = kgd & 31u, d = kgd >> 5;
  const float* src = W + (size_t)(d * 256u + o) * CIN + kg * 8u;
  float4 f0 = ((const float4*)src)[0];
  float4 f1 = ((const float4*)src)[1];
  u16x8 v;
  v[0] = f2bf(f0.x); v[1] = f2bf(f0.y); v[2] = f2bf(f0.z); v[3] = f2bf(f0.w);
  v[4] = f2bf(f1.x); v[5] = f2bf(f1.y); v[6] = f2bf(f1.z); v[7] = f2bf(f1.w);
  *(u16x8*)(wb + (size_t)idx * 8) = v;
}

// ------- x (b,i,t,r,c) fp32 -> xt2[b][kg][p][8] bf16 ------------------------
__global__ void transpose_pad(const float* __restrict__ x, u16* __restrict__ xt) {
  __shared__ __align__(16) u16 tile[32][256];
  u32 wg = blockIdx.x;                       // 2048 = B*32*32
  u32 b = wg >> 10, t = (wg >> 5) & 31, r = wg & 31;
  u32 i = threadIdx.x;
  const float* src = x + ((size_t)(b * CIN + i) * SPAT + t * 1024u + r * 32u);
#pragma unroll
  for (int q = 0; q < 8; ++q) {
    float4 f = ((const float4*)src)[q];
    tile[q * 4 + 0][i] = f2bf(f.x);
    tile[q * 4 + 1][i] = f2bf(f.y);
    tile[q * 4 + 2][i] = f2bf(f.z);
    tile[q * 4 + 3][i] = f2bf(f.w);
  }
  __syncthreads();
  u32 c = threadIdx.x >> 3, chunk = threadIdx.x & 7;   // chunk -> kg 4*chunk..+3
  u32 p = ((t + 1) * PD + (r + 1)) * PD + 1 + c;
  const uint4* s = (const uint4*)&tile[c][chunk * 32u];
#pragma unroll
  for (int j = 0; j < 4; ++j) {
    u32 kg = chunk * 4u + (u32)j;
    *(uint4*)(xt + ((size_t)(b * 32u + kg) * P3 + p) * 8) = s[j];
  }
}

// ---------------- main: 8-wave 256x256 tile, 32x32x16, reg-pipelined --------
// 28 K-tiles of BK=64. Per tile: STAGE(T+1) issued at tile TOP (full tile to
// land -> the tile-end __syncthreads vmcnt drain is ~free), then a register-
// pipelined ks loop: rd0,rd1,mm0,rd2,mm1,rd3,mm2,mm3 - LDS pipe streams
// continuously under the MFMAs instead of bursting between barriers.
// ONE barrier per tile.
__global__ __launch_bounds__(512, 2)
void conv_main(const u16* __restrict__ xt, const u16* __restrict__ wb,
               float* __restrict__ out) {
  // [buf][A=0/B=1][kb(8)][row'(256)][8]  = 128 KiB
  __shared__ __align__(16) u16 lds[2][2][8][256][8];

  u32 bid = blockIdx.x;
  u32 id2 = (bid & 7) * 32u + (bid >> 3);    // XCD swizzle (256 % 8 == 0)
  u32 b  = id2 >> 7;
  u32 t  = (id2 >> 2) & 31;
  u32 r0 = (id2 & 3) * 8u;

  u32 tid = threadIdx.x;
  u32 lane = tid & 63, wave = tid >> 6;
  u32 wm = wave >> 2, wn = wave & 3;         // 2(m) x 4(n) wave grid
  u32 l31 = lane & 31u, lhalf = lane >> 5;

  const u16* xb = xt + (size_t)b * 32u * P3 * 8u;
  u32 pBase = ((t + 1) * PD + (r0 + 1)) * PD + 1;

  u32 aLane = lane * 8u;                                   // u16 units
  u32 bLane = (2u * (lane >> 5) * (u32)PD + (lane & 31u)) * 8u;

  // A rows' H*128 + c*64 + l  <->  W cout (2c+H)*64 + l   (verified R7)
#define STAGE_A(KN, H) do {                                                   \
    u32 kn_ = (u32)(KN);                                                      \
    const u16* g_ = wb + ((size_t)((kn_ >> 2) * 32u + (kn_ & 3u) * 8u + wave) \
                          * 256u + (H) * 64u) * 8u + aLane;                   \
    u16* d_ = &lds[kn_ & 1u][0][wave][(H) * 128][0];                          \
    gload_lds16(g_, d_);                                                      \
    gload_lds16(g_ + 1024u, d_ + 512u);                                       \
  } while (0)

  // B rows' H*128 + c*64 + l <-> n = (2c+(l>>5))*64 + H*32 + (l&31) (verified R7)
#define STAGE_B(KN, H) do {                                                   \
    u32 kn_ = (u32)(KN);                                                      \
    u32 kg_ = (kn_ & 3u) * 8u + wave;                                         \
    const u16* g_ = xb + ((size_t)kg_ * P3                                    \
                          + (u32)((int)pBase + tapOff(kn_ >> 2))              \
                          + (H) * (u32)PD) * 8u + bLane;                      \
    u16* d_ = &lds[kn_ & 1u][1][wave][(H) * 128][0];                          \
    gload_lds16(g_, d_);                                                      \
    gload_lds16(g_ + (u32)(4 * PD * 8), d_ + 512u);                           \
  } while (0)

#define STAGE(KN) do { STAGE_A(KN, 0); STAGE_A(KN, 1);                        \
                       STAGE_B(KN, 0); STAGE_B(KN, 1); } while (0)

  // frag reads for one ks (K=16): 4 A + 2 B ds_read_b128.
  // A frag (ks,mt): cout = wm*128+mt*32+l31 -> row' = (mt>>1)*128+wm*64+(mt&1)*32+l31
  // B frag (ks,nt): n = wn*64+nt*32+l31     -> row' = nt*128+wn*32+l31
  // kb = ks*2 + lhalf.
#define RD(AS, BS, KS) do {                                                   \
    u32 kb_ = (u32)(KS) * 2u + lhalf;                                         \
    _Pragma("unroll")                                                         \
    for (int mt = 0; mt < 4; ++mt)                                            \
      AS[mt] = *(const bf16x8*)&lds[buf][0][kb_]                              \
          [(mt >> 1) * 128 + wm * 64 + (mt & 1) * 32 + l31][0];               \
    _Pragma("unroll")                                                         \
    for (int nt = 0; nt < 2; ++nt)                                            \
      BS[nt] = *(const bf16x8*)&lds[buf][1][kb_]                              \
          [nt * 128 + wn * 32 + l31][0];                                      \
  } while (0)

#define MF(A, Bv, C) __builtin_amdgcn_mfma_f32_32x32x16_bf16(A, Bv, C, 0, 0, 0)

#define MM(AS, BS) do {                                                       \
    __builtin_amdgcn_s_setprio(1);                                            \
    _Pragma("unroll")                                                         \
    for (int mt = 0; mt < 4; ++mt)                                            \
      _Pragma("unroll")                                                       \
      for (int nt = 0; nt < 2; ++nt)                                          \
        acc[mt][nt] = MF(AS[mt], BS[nt], acc[mt][nt]);                        \
    __builtin_amdgcn_s_setprio(0);                                            \
  } while (0)

  f32x16 acc[4][2];
#pragma unroll
  for (int i = 0; i < 4; ++i)
#pragma unroll
    for (int j = 0; j < 2; ++j) acc[i][j] = (f32x16)0.0f;

  bf16x8 aX[4], bX[2], aY[4], bY[2];

  STAGE(0);
  __syncthreads();                 // drains vmcnt(0): buf0 ready

#pragma unroll 1
  for (int T = 0; T < 28; ++T) {
    const u32 buf = (u32)T & 1u;
    if (T + 1 < 28) STAGE(T + 1);  // issue-first: a full tile to land
    RD(aX, bX, 0);
    RD(aY, bY, 1);
    MM(aX, bX);                    // ks0 (ks1 reads still in flight)
    RD(aX, bX, 2);
    MM(aY, bY);                    // ks1
    RD(aY, bY, 3);
    MM(aX, bX);                    // ks2
    MM(aY, bY);                    // ks3
    if (T + 1 < 28) __syncthreads();  // vmcnt(0)+lgkmcnt(0)+s_barrier
  }

#undef MM
#undef MF
#undef RD
#undef STAGE
#undef STAGE_B
#undef STAGE_A

  // epilogue: 32x32 C/D: col = lane&31 (spatial), row = (reg&3)+8*(reg>>2)
  //           +4*(lane>>5) (cout within 32)   (verified R4)
  u32 rbase = lhalf * 4u;
  float* ob = out + (size_t)(b * COUT + wm * 128u) * SPAT
                  + t * 1024u + r0 * 32u;
#pragma unroll
  for (int mt = 0; mt < 4; ++mt)
#pragma unroll
    for (int nt = 0; nt < 2; ++nt) {
      f32x16 v = acc[mt][nt];
#pragma unroll
      for (int reg = 0; reg < 16; ++reg) {
        u32 row = (u32)(reg & 3) + 8u * (u32)(reg >> 2) + rbase;
        ob[(size_t)(mt * 32u + row) * SPAT + wn * 64u + nt * 32u + l31] = v[reg];
      }
    }
}

extern "C" void kernel_launch(void* const* d_in, const int* in_sizes, int n_in,
                              void* d_out, int out_size, void* d_ws, size_t ws_size,
                              hipStream_t stream) {
  const float* x = (const float*)d_in[0];
  const float* W = (const float*)d_in[1];
  float* out = (float*)d_out;
  u16* xt  = (u16*)d_ws;
  u16* wbf = (u16*)((char*)d_ws + WB_OFF_BYTES);

  u32 zThreads = 64u * (u32)P3;
  hipLaunchKernelGGL(zero_border,   dim3((zThreads + 255) / 256), dim3(256), 0, stream, xt);
  hipLaunchKernelGGL(convert_w,     dim3(224),  dim3(256), 0, stream, W, wbf);
  hipLaunchKernelGGL(transpose_pad, dim3(2048), dim3(256), 0, stream, x, xt);
  hipLaunchKernelGGL(conv_main,     dim3(256),  dim3(512), 0, stream, xt, wbf, out);
}

// Round 10
// 93.726 us; speedup vs baseline: 1.1261x; 1.0305x over previous
//
#include <hip/hip_runtime.h>

typedef unsigned int u32;
typedef unsigned short u16;

#define B_   2
#define CIN  256
#define COUT 256
#define PD   34
#define PLANE (PD*PD)        // 1156
#define P3   (PD*PD*PD)      // 39304
#define SPAT 32768           // 32*32*32

// xt2: [b][kg(32)][p(P3)][8]  (granule = 8 cin = 16B)
#define XT_BYTES ((size_t)B_ * 32 * P3 * 8 * 2)
#define WB_OFF_BYTES XT_BYTES

typedef __attribute__((ext_vector_type(8)))  short bf16x8;
typedef __attribute__((ext_vector_type(8)))  u16   u16x8;
typedef __attribute__((ext_vector_type(16))) float f32x16;

__device__ __forceinline__ u16 f2bf(float f) {
  union { float f; u32 u; } v; v.f = f;
  u32 r = v.u + 0x7FFFu + ((v.u >> 16) & 1u);   // RNE
  return (u16)(r >> 16);
}

__device__ __forceinline__ void gload_lds16(const void* g, void* l) {
  __builtin_amdgcn_global_load_lds(
      (const __attribute__((address_space(1))) u32*)g,
      (__attribute__((address_space(3))) u32*)l,
      16, 0, 0);
}

__device__ __forceinline__ int tapOff(u32 d) {
  return (d == 1) ? -PLANE : (d == 2) ? PLANE
       : (d == 3) ? -PD    : (d == 4) ? PD
       : (d == 5) ? -1     : (d == 6) ? 1 : 0;
}

// ---------------- zero only the pad border of xt2 ---------------------------
__global__ void zero_border(u16* __restrict__ xt) {
  u32 idx = blockIdx.x * 256u + threadIdx.x;   // 64 * P3 granules
  if (idx >= 64u * (u32)P3) return;
  u32 bk = idx & 63u;                          // b*32 + kg
  u32 p  = idx >> 6;
  u32 t = p / PLANE, rem = p - t * PLANE, r = rem / PD, c = rem - r * PD;
  if (!((t == 0) | (t == 33) | (r == 0) | (r == 33) | (c == 0) | (c == 33)))
    return;
  *(u16x8*)(xt + ((size_t)bk * P3 + p) * 8) = (u16x8)0;
}

// ---------------- W fp32 -> bf16, wb2[d][kg][o][8] ---------------------------
__global__ void convert_w(const float* __restrict__ W, u16* __restrict__ wb) {
  u32 idx = blockIdx.x * 256u + threadIdx.x;   // 7*32*256 = 57344
  u32 o = idx & 255u, kgd = idx >> 8;          // kgd = d*32 + kg
  u32 kg = kgd & 31u, d = kgd >> 5;
  const float* src = W + (size_t)(d * 256u + o) * CIN + kg * 8u;
  float4 f0 = ((const float4*)src)[0];
  float4 f1 = ((const float4*)src)[1];
  u16x8 v;
  v[0] = f2bf(f0.x); v[1] = f2bf(f0.y); v[2] = f2bf(f0.z); v[3] = f2bf(f0.w);
  v[4] = f2bf(f1.x); v[5] = f2bf(f1.y); v[6] = f2bf(f1.z); v[7] = f2bf(f1.w);
  *(u16x8*)(wb + (size_t)idx * 8) = v;
}

// ------- x (b,i,t,r,c) fp32 -> xt2[b][kg][p][8], COALESCED ------------------
// lane = spatial (c,r): wave reads 1KB contiguous per channel; writes 512B runs.
__global__ void transpose_pad(const float* __restrict__ x, u16* __restrict__ xt) {
  u32 wg = blockIdx.x;                 // 1024 = b(2) x t(32) x rq(4) x ih(4)
  u32 ih = wg & 3u, rq = (wg >> 2) & 3u, t = (wg >> 4) & 31u, b = wg >> 9;
  u32 tid = threadIdx.x;
  u32 r = tid >> 5, c = tid & 31u, rr = rq * 8u + r;
  u32 sOff = t * 1024u + rr * 32u + c;
  u32 p = ((t + 1) * PD + (rr + 1)) * PD + 1 + c;
#pragma unroll 1
  for (u32 g = 0; g < 8; ++g) {
    u32 ig = ih * 8u + g;
    u16x8 v;
#pragma unroll
    for (int j = 0; j < 8; ++j)
      v[j] = f2bf(x[(size_t)(b * 256u + ig * 8u + (u32)j) * SPAT + sOff]);
    *(u16x8*)(xt + ((size_t)(b * 32u + ig) * P3 + p) * 8) = v;
  }
}

// ---------------- main: 8-wave 256x256 tile, 32x32x16, TRIPLE-buffered ------
// 56 K-tiles of BK=32, 3 LDS buffers (96 KiB). Top of tile T stages tile T+2
// (4 gload_lds/wave) -> loads get a 2-tile deadline. End-of-tile sync =
// vmcnt(4) (only the just-issued batch outstanding) + s_barrier; vmcnt(0)
// only at the tail. 12 ds_read_b128 + 16 MFMA 32x32x16 per wave per tile.
__global__ __launch_bounds__(512, 2)
void conv_main(const u16* __restrict__ xt, const u16* __restrict__ wb,
               float* __restrict__ out) {
  // [buf3][A=0/B=1][kb(4)][row'(256)][8]  = 96 KiB
  __shared__ __align__(16) u16 lds[3][2][4][256][8];

  u32 bid = blockIdx.x;
  u32 id2 = (bid & 7) * 32u + (bid >> 3);    // XCD swizzle (256 % 8 == 0)
  u32 b  = id2 >> 7;
  u32 t  = (id2 >> 2) & 31;
  u32 r0 = (id2 & 3) * 8u;

  u32 tid = threadIdx.x;
  u32 lane = tid & 63, wave = tid >> 6;
  u32 wm = wave >> 2, wn = wave & 3;         // 2(m) x 4(n) wave grid
  u32 l31 = lane & 31u, lh = lane >> 5;
  u32 kbw = wave & 3u, Hw = wave >> 2;       // staging role

  const u16* xb = xt + (size_t)b * 32u * P3 * 8u;
  u32 pBase = ((t + 1) * PD + (r0 + 1)) * PD + 1;

  // A rows' H*128 + c*64 + l <-> cout (2c+H)*64 + l   (verified R7/R9)
  // B rows' H*128 + j*64 + l <-> n = (2j+(l>>5))*64 + H*32 + (l&31)
#define STAGE(T_, BUF_) do {                                                  \
    u32 Tn_ = (u32)(T_);                                                      \
    u32 d_ = Tn_ >> 3, kg_ = (Tn_ & 7u) * 4u + kbw;                           \
    const u16* gA_ = wb + ((size_t)(d_ * 32u + kg_) * 256u + Hw * 64u) * 8u   \
                        + lane * 8u;                                          \
    u16* dA_ = &lds[BUF_][0][kbw][Hw * 128u][0];                              \
    gload_lds16(gA_,          dA_);                                           \
    gload_lds16(gA_ + 1024u,  dA_ + 512u);                                    \
    const u16* gB_ = xb + (size_t)kg_ * P3 * 8u                               \
        + (ptrdiff_t)(((int)pBase + tapOff(d_)                                \
                       + (int)(lh * 2u * PD + Hw * PD + l31)) * 8);           \
    u16* dB_ = &lds[BUF_][1][kbw][Hw * 128u][0];                              \
    gload_lds16(gB_,                    dB_);                                 \
    gload_lds16(gB_ + 4u * PD * 8u,     dB_ + 512u);                          \
  } while (0)

  // frag reads for one ks (K=16): 4 A + 2 B ds_read_b128; kb = ks*2 + lh
#define RD(AS, BS, KS) do {                                                   \
    u32 kb_ = (u32)(KS) * 2u + lh;                                            \
    _Pragma("unroll")                                                         \
    for (int mt = 0; mt < 4; ++mt)                                            \
      AS[mt] = *(const bf16x8*)&lds[bcur][0][kb_]                             \
          [(mt >> 1) * 128 + wm * 64 + (mt & 1) * 32 + l31][0];               \
    _Pragma("unroll")                                                         \
    for (int nt = 0; nt < 2; ++nt)                                            \
      BS[nt] = *(const bf16x8*)&lds[bcur][1][kb_]                             \
          [nt * 128 + wn * 32 + l31][0];                                      \
  } while (0)

#define MF(A, Bv, C) __builtin_amdgcn_mfma_f32_32x32x16_bf16(A, Bv, C, 0, 0, 0)

#define MM(AS, BS) do {                                                       \
    __builtin_amdgcn_s_setprio(1);                                            \
    _Pragma("unroll")                                                         \
    for (int mt = 0; mt < 4; ++mt)                                            \
      _Pragma("unroll")                                                       \
      for (int nt = 0; nt < 2; ++nt)                                          \
        acc[mt][nt] = MF(AS[mt], BS[nt], acc[mt][nt]);                        \
    __builtin_amdgcn_s_setprio(0);                                            \
  } while (0)

  f32x16 acc[4][2];
#pragma unroll
  for (int i = 0; i < 4; ++i)
#pragma unroll
    for (int j = 0; j < 2; ++j) acc[i][j] = (f32x16)0.0f;

  bf16x8 aX[4], bX[2], aY[4], bY[2];

  // prologue: stage tiles 0 and 1; wait tile-0 batch (allow tile-1's 4)
  STAGE(0, 0);
  STAGE(1, 1);
  __builtin_amdgcn_sched_barrier(0);
  asm volatile("s_waitcnt vmcnt(4)" ::: "memory");
  __builtin_amdgcn_s_barrier();
  __builtin_amdgcn_sched_barrier(0);

  u32 bcur = 0;
#pragma unroll 1
  for (int T = 0; T < 56; ++T) {
    u32 bstg = bcur + 2u; if (bstg >= 3u) bstg -= 3u;
    if (T + 2 < 56) STAGE(T + 2, bstg);
    RD(aX, bX, 0);
    RD(aY, bY, 1);
    MM(aX, bX);
    MM(aY, bY);
    __builtin_amdgcn_sched_barrier(0);
    if (T < 54)       asm volatile("s_waitcnt vmcnt(4)" ::: "memory");
    else if (T == 54) asm volatile("s_waitcnt vmcnt(0)" ::: "memory");
    if (T < 55) {
      __builtin_amdgcn_s_barrier();
      __builtin_amdgcn_sched_barrier(0);
    }
    bcur = (bcur == 2u) ? 0u : bcur + 1u;
  }

#undef MM
#undef MF
#undef RD
#undef STAGE

  // epilogue: 32x32 C/D: col = lane&31 (spatial), row = (reg&3)+8*(reg>>2)
  //           +4*(lane>>5) (cout within 32)   (verified R4/R9)
  u32 rbase = lh * 4u;
  float* ob = out + (size_t)(b * COUT + wm * 128u) * SPAT
                  + t * 1024u + r0 * 32u;
#pragma unroll
  for (int mt = 0; mt < 4; ++mt)
#pragma unroll
    for (int nt = 0; nt < 2; ++nt) {
      f32x16 v = acc[mt][nt];
#pragma unroll
      for (int reg = 0; reg < 16; ++reg) {
        u32 row = (u32)(reg & 3) + 8u * (u32)(reg >> 2) + rbase;
        ob[(size_t)(mt * 32u + row) * SPAT + wn * 64u + nt * 32u + l31] = v[reg];
      }
    }
}

extern "C" void kernel_launch(void* const* d_in, const int* in_sizes, int n_in,
                              void* d_out, int out_size, void* d_ws, size_t ws_size,
                              hipStream_t stream) {
  const float* x = (const float*)d_in[0];
  const float* W = (const float*)d_in[1];
  float* out = (float*)d_out;
  u16* xt  = (u16*)d_ws;
  u16* wbf = (u16*)((char*)d_ws + WB_OFF_BYTES);

  u32 zThreads = 64u * (u32)P3;
  hipLaunchKernelGGL(zero_border,   dim3((zThreads + 255) / 256), dim3(256), 0, stream, xt);
  hipLaunchKernelGGL(convert_w,     dim3(224),  dim3(256), 0, stream, W, wbf);
  hipLaunchKernelGGL(transpose_pad, dim3(1024), dim3(256), 0, stream, x, xt);
  hipLaunchKernelGGL(conv_main,     dim3(256),  dim3(512), 0, stream, xt, wbf, out);
}

// Round 11
// 91.941 us; speedup vs baseline: 1.1480x; 1.0194x over previous
//
#include <hip/hip_runtime.h>

typedef unsigned int u32;
typedef unsigned short u16;

#define B_   2
#define CIN  256
#define COUT 256
#define PD   34
#define PLANE (PD*PD)        // 1156
#define P3   (PD*PD*PD)      // 39304
#define SPAT 32768           // 32*32*32

// xt2: [b][kg(32)][p(P3)][8]  (granule = 8 cin = 16B)
#define XT_BYTES ((size_t)B_ * 32 * P3 * 8 * 2)
#define WB_OFF_BYTES XT_BYTES

typedef __attribute__((ext_vector_type(8)))  short bf16x8;
typedef __attribute__((ext_vector_type(8)))  u16   u16x8;
typedef __attribute__((ext_vector_type(16))) float f32x16;

__device__ __forceinline__ u16 f2bf(float f) {
  union { float f; u32 u; } v; v.f = f;
  u32 r = v.u + 0x7FFFu + ((v.u >> 16) & 1u);   // RNE
  return (u16)(r >> 16);
}

__device__ __forceinline__ void gload_lds16(const void* g, void* l) {
  __builtin_amdgcn_global_load_lds(
      (const __attribute__((address_space(1))) u32*)g,
      (__attribute__((address_space(3))) u32*)l,
      16, 0, 0);
}

__device__ __forceinline__ int tapOff(u32 d) {
  return (d == 1) ? -PLANE : (d == 2) ? PLANE
       : (d == 3) ? -PD    : (d == 4) ? PD
       : (d == 5) ? -1     : (d == 6) ? 1 : 0;
}

// ---------------- zero only the pad border of xt2 ---------------------------
__global__ void zero_border(u16* __restrict__ xt) {
  u32 idx = blockIdx.x * 256u + threadIdx.x;   // 64 * P3 granules
  if (idx >= 64u * (u32)P3) return;
  u32 bk = idx & 63u;                          // b*32 + kg
  u32 p  = idx >> 6;
  u32 t = p / PLANE, rem = p - t * PLANE, r = rem / PD, c = rem - r * PD;
  if (!((t == 0) | (t == 33) | (r == 0) | (r == 33) | (c == 0) | (c == 33)))
    return;
  *(u16x8*)(xt + ((size_t)bk * P3 + p) * 8) = (u16x8)0;
}

// ---------------- W fp32 -> bf16, wb2[d][kg][o][8] ---------------------------
__global__ void convert_w(const float* __restrict__ W, u16* __restrict__ wb) {
  u32 idx = blockIdx.x * 256u + threadIdx.x;   // 7*32*256 = 57344
  u32 o = idx & 255u, kgd = idx >> 8;          // kgd = d*32 + kg
  u32 kg = kgd & 31u, d = kgd >> 5;
  const float* src = W + (size_t)(d * 256u + o) * CIN + kg * 8u;
  float4 f0 = ((const float4*)src)[0];
  float4 f1 = ((const float4*)src)[1];
  u16x8 v;
  v[0] = f2bf(f0.x); v[1] = f2bf(f0.y); v[2] = f2bf(f0.z); v[3] = f2bf(f0.w);
  v[4] = f2bf(f1.x); v[5] = f2bf(f1.y); v[6] = f2bf(f1.z); v[7] = f2bf(f1.w);
  *(u16x8*)(wb + (size_t)idx * 8) = v;
}

// ------- x (b,i,t,r,c) fp32 -> xt2[b][kg][p][8], COALESCED ------------------
__global__ void transpose_pad(const float* __restrict__ x, u16* __restrict__ xt) {
  u32 wg = blockIdx.x;                 // 1024 = b(2) x t(32) x rq(4) x ih(4)
  u32 ih = wg & 3u, rq = (wg >> 2) & 3u, t = (wg >> 4) & 31u, b = wg >> 9;
  u32 tid = threadIdx.x;
  u32 r = tid >> 5, c = tid & 31u, rr = rq * 8u + r;
  u32 sOff = t * 1024u + rr * 32u + c;
  u32 p = ((t + 1) * PD + (rr + 1)) * PD + 1 + c;
#pragma unroll 1
  for (u32 g = 0; g < 8; ++g) {
    u32 ig = ih * 8u + g;
    u16x8 v;
#pragma unroll
    for (int j = 0; j < 8; ++j)
      v[j] = f2bf(x[(size_t)(b * 256u + ig * 8u + (u32)j) * SPAT + sOff]);
    *(u16x8*)(xt + ((size_t)(b * 32u + ig) * P3 + p) * 8) = v;
  }
}

// ---------------- main: 8-wave 256x256 tile, 32x32x16, dbuf BK=64 -----------
// R9 structure + T19 sched_group_barrier pinning per-tile emission order:
// [8 VMEM stage][rd6 ks0][rd6 ks1][mfma8 ks0][rd6 ks2][mfma8 ks1][rd6 ks3]
// [mfma8 ks2][mfma8 ks3] -- ds_reads of ks_{i+1} drain in the LDS pipe while
// MFMA ks_i issues (breaks the compiler's read-bulk-then-MFMA serialization).
__global__ __launch_bounds__(512, 2)
void conv_main(const u16* __restrict__ xt, const u16* __restrict__ wb,
               float* __restrict__ out) {
  // [buf][A=0/B=1][kb(8)][row'(256)][8]  = 128 KiB
  __shared__ __align__(16) u16 lds[2][2][8][256][8];

  u32 bid = blockIdx.x;
  u32 id2 = (bid & 7) * 32u + (bid >> 3);    // XCD swizzle (256 % 8 == 0)
  u32 b  = id2 >> 7;
  u32 t  = (id2 >> 2) & 31;
  u32 r0 = (id2 & 3) * 8u;

  u32 tid = threadIdx.x;
  u32 lane = tid & 63, wave = tid >> 6;
  u32 wm = wave >> 2, wn = wave & 3;         // 2(m) x 4(n) wave grid
  u32 l31 = lane & 31u, lh = lane >> 5;

  const u16* xb = xt + (size_t)b * 32u * P3 * 8u;
  u32 pBase = ((t + 1) * PD + (r0 + 1)) * PD + 1;

  u32 aLane = lane * 8u;                                   // u16 units
  u32 bLane = (2u * (lane >> 5) * (u32)PD + (lane & 31u)) * 8u;

  // A rows' H*128 + c*64 + l  <->  W cout (2c+H)*64 + l   (verified R7/R9)
#define STAGE_A(KN, H) do {                                                   \
    u32 kn_ = (u32)(KN);                                                      \
    const u16* g_ = wb + ((size_t)((kn_ >> 2) * 32u + (kn_ & 3u) * 8u + wave) \
                          * 256u + (H) * 64u) * 8u + aLane;                   \
    u16* d_ = &lds[kn_ & 1u][0][wave][(H) * 128][0];                          \
    gload_lds16(g_, d_);                                                      \
    gload_lds16(g_ + 1024u, d_ + 512u);                                       \
  } while (0)

  // B rows' H*128 + c*64 + l <-> n = (2c+(l>>5))*64 + H*32 + (l&31) (verified)
#define STAGE_B(KN, H) do {                                                   \
    u32 kn_ = (u32)(KN);                                                      \
    u32 kg_ = (kn_ & 3u) * 8u + wave;                                         \
    const u16* g_ = xb + ((size_t)kg_ * P3                                    \
                          + (u32)((int)pBase + tapOff(kn_ >> 2))              \
                          + (H) * (u32)PD) * 8u + bLane;                      \
    u16* d_ = &lds[kn_ & 1u][1][wave][(H) * 128][0];                          \
    gload_lds16(g_, d_);                                                      \
    gload_lds16(g_ + (u32)(4 * PD * 8), d_ + 512u);                           \
  } while (0)

#define STAGE(KN) do { STAGE_A(KN, 0); STAGE_A(KN, 1);                        \
                       STAGE_B(KN, 0); STAGE_B(KN, 1); } while (0)

  // frag reads for one ks (K=16): 4 A + 2 B ds_read_b128; kb = ks*2 + lh
#define RD(AS, BS, KS) do {                                                   \
    u32 kb_ = (u32)(KS) * 2u + lh;                                            \
    _Pragma("unroll")                                                         \
    for (int mt = 0; mt < 4; ++mt)                                            \
      AS[mt] = *(const bf16x8*)&lds[buf][0][kb_]                              \
          [(mt >> 1) * 128 + wm * 64 + (mt & 1) * 32 + l31][0];               \
    _Pragma("unroll")                                                         \
    for (int nt = 0; nt < 2; ++nt)                                            \
      BS[nt] = *(const bf16x8*)&lds[buf][1][kb_]                              \
          [nt * 128 + wn * 32 + l31][0];                                      \
  } while (0)

#define MF(A, Bv, C) __builtin_amdgcn_mfma_f32_32x32x16_bf16(A, Bv, C, 0, 0, 0)

#define MM(AS, BS) do {                                                       \
    __builtin_amdgcn_s_setprio(1);                                            \
    _Pragma("unroll")                                                         \
    for (int mt = 0; mt < 4; ++mt)                                            \
      _Pragma("unroll")                                                       \
      for (int nt = 0; nt < 2; ++nt)                                          \
        acc[mt][nt] = MF(AS[mt], BS[nt], acc[mt][nt]);                        \
    __builtin_amdgcn_s_setprio(0);                                            \
  } while (0)

#define SGB(MASK, N) __builtin_amdgcn_sched_group_barrier((MASK), (N), 0)

  f32x16 acc[4][2];
#pragma unroll
  for (int i = 0; i < 4; ++i)
#pragma unroll
    for (int j = 0; j < 2; ++j) acc[i][j] = (f32x16)0.0f;

  bf16x8 aX[4], bX[2], aY[4], bY[2];

  STAGE(0);
  __syncthreads();                 // drains vmcnt(0): buf0 ready

#pragma unroll 1
  for (int T = 0; T < 28; ++T) {
    const u32 buf = (u32)T & 1u;
    if (T + 1 < 28) STAGE(T + 1);  // issue-first: a full tile to land
    RD(aX, bX, 0);
    RD(aY, bY, 1);
    MM(aX, bX);                    // ks0
    RD(aX, bX, 2);
    MM(aY, bY);                    // ks1
    RD(aY, bY, 3);
    MM(aX, bX);                    // ks2
    MM(aY, bY);                    // ks3
    // T19: pin emission order -- stage first, then rd/mfma interleaved
    SGB(0x70, 8);                  // 8 VMEM (global_load_lds)
    SGB(0x100, 6);                 // ds_read ks0
    SGB(0x100, 6);                 // ds_read ks1
    SGB(0x8, 8);                   // mfma ks0
    SGB(0x100, 6);                 // ds_read ks2
    SGB(0x8, 8);                   // mfma ks1
    SGB(0x100, 6);                 // ds_read ks3
    SGB(0x8, 8);                   // mfma ks2
    SGB(0x8, 8);                   // mfma ks3
    if (T + 1 < 28) __syncthreads();
  }

#undef SGB
#undef MM
#undef MF
#undef RD
#undef STAGE
#undef STAGE_B
#undef STAGE_A

  // epilogue: 32x32 C/D: col = lane&31 (spatial), row = (reg&3)+8*(reg>>2)
  //           +4*(lane>>5) (cout within 32)   (verified R4/R9)
  u32 rbase = lh * 4u;
  float* ob = out + (size_t)(b * COUT + wm * 128u) * SPAT
                  + t * 1024u + r0 * 32u;
#pragma unroll
  for (int mt = 0; mt < 4; ++mt)
#pragma unroll
    for (int nt = 0; nt < 2; ++nt) {
      f32x16 v = acc[mt][nt];
#pragma unroll
      for (int reg = 0; reg < 16; ++reg) {
        u32 row = (u32)(reg & 3) + 8u * (u32)(reg >> 2) + rbase;
        ob[(size_t)(mt * 32u + row) * SPAT + wn * 64u + nt * 32u + l31] = v[reg];
      }
    }
}

extern "C" void kernel_launch(void* const* d_in, const int* in_sizes, int n_in,
                              void* d_out, int out_size, void* d_ws, size_t ws_size,
                              hipStream_t stream) {
  const float* x = (const float*)d_in[0];
  const float* W = (const float*)d_in[1];
  float* out = (float*)d_out;
  u16* xt  = (u16*)d_ws;
  u16* wbf = (u16*)((char*)d_ws + WB_OFF_BYTES);

  u32 zThreads = 64u * (u32)P3;
  hipLaunchKernelGGL(zero_border,   dim3((zThreads + 255) / 256), dim3(256), 0, stream, xt);
  hipLaunchKernelGGL(convert_w,     dim3(224),  dim3(256), 0, stream, W, wbf);
  hipLaunchKernelGGL(transpose_pad, dim3(1024), dim3(256), 0, stream, x, xt);
  hipLaunchKernelGGL(conv_main,     dim3(256),  dim3(512), 0, stream, xt, wbf, out);
}